// Round 4
// baseline (1302.871 us; speedup 1.0000x reference)
//
#include <hip/hip_runtime.h>
#include <hip/hip_bf16.h>

typedef __hip_bfloat16 bf16;

#define B_   2
#define C_   128
#define H_   256
#define W_   256
#define HW_  65536
#define HD_  8
#define CH_  16
#define C3_  384

static __device__ __forceinline__ float b2f(bf16 v) { return __bfloat162float(v); }
static __device__ __forceinline__ bf16  f2b(float v) { return __float2bfloat16(v); }

// generic load/store: T is the external (input/output) dtype
template<typename T> static __device__ __forceinline__ float ldg(const void* p, size_t i);
template<> __device__ __forceinline__ float ldg<float>(const void* p, size_t i) { return ((const float*)p)[i]; }
template<> __device__ __forceinline__ float ldg<bf16 >(const void* p, size_t i) { return b2f(((const bf16*)p)[i]); }
template<typename T> static __device__ __forceinline__ void stg(void* p, size_t i, float v);
template<> __device__ __forceinline__ void stg<float>(void* p, size_t i, float v) { ((float*)p)[i] = v; }
template<> __device__ __forceinline__ void stg<bf16 >(void* p, size_t i, float v) { ((bf16*)p)[i] = f2b(v); }
template<typename T> struct DtF { static constexpr int v = 0; };
template<> struct DtF<float> { static constexpr int v = 1; };

// ------------------------------------------------- dtype probe (temperature==1)
__global__ void k_probe(const unsigned int* __restrict__ traw, int* __restrict__ flag) {
  if (threadIdx.x == 0 && blockIdx.x == 0)
    *flag = (traw[0] == 0x3F800000u) ? 1 : 0;   // f32 pattern of 1.0f
}

// ---------------------------------------------------------------- weight prep
template<typename T>
__global__ void k_wprep(const int* __restrict__ flag,
                        const void* __restrict__ qkv_w, const void* __restrict__ proj_w,
                        const void* __restrict__ sa_w1,
                        float* __restrict__ wt_qkvT, float* __restrict__ wt_proj,
                        float* __restrict__ wt_sa1) {
  if (*flag != DtF<T>::v) return;
  int idx = blockIdx.x * 256 + threadIdx.x;
  if (idx < C3_ * C_) { int o = idx / C_, i = idx % C_; wt_qkvT[i * C3_ + o] = ldg<T>(qkv_w, idx); }
  if (idx < C_ * C_)  { int o = idx / C_, i = idx % C_; wt_proj[i * C_ + o] = ldg<T>(proj_w, idx); }
  if (idx < 16 * C_)  { int j = idx / C_, i = idx % C_; wt_sa1[i * 16 + j] = ldg<T>(sa_w1, idx); }
}

// ------------------------------------------------------------ spatial gate sa
template<typename T>
__global__ void k_sa(const int* __restrict__ flag,
                     const void* __restrict__ y, const float* __restrict__ wt_sa1,
                     const void* __restrict__ sa_w2, const void* __restrict__ sa_w3,
                     float* __restrict__ sa) {
  if (*flag != DtF<T>::v) return;
  int b = blockIdx.y;
  int pos = blockIdx.x * 256 + threadIdx.x;
  size_t ybase = (size_t)b * C_ * HW_ + pos;
  float t1[16];
#pragma unroll
  for (int j = 0; j < 16; ++j) t1[j] = 0.f;
  for (int i = 0; i < C_; ++i) {
    float yv = ldg<T>(y, ybase + (size_t)i * HW_);
    const float* wr = wt_sa1 + i * 16;   // wave-uniform -> s_load
#pragma unroll
    for (int j = 0; j < 16; ++j) t1[j] = fmaf(wr[j], yv, t1[j]);
  }
#pragma unroll
  for (int j = 0; j < 16; ++j) t1[j] = fmaxf(t1[j], 0.f);
  float t2[16];
#pragma unroll
  for (int j = 0; j < 16; ++j) {
    float s = 0.f;
#pragma unroll
    for (int l = 0; l < 16; ++l) s = fmaf(ldg<T>(sa_w2, j * 16 + l), t1[l], s);
    t2[j] = fmaxf(s, 0.f);
  }
  float s3 = 0.f;
#pragma unroll
  for (int j = 0; j < 16; ++j) s3 = fmaf(ldg<T>(sa_w3, j), t2[j], s3);
  sa[(size_t)b * HW_ + pos] = 1.f / (1.f + expf(-s3));
}

// ------- fused conv1x1(q,k) on-the-fly + dw3x3 + sa-gate + gram + sumsq -----
template<typename T>
__global__ void __launch_bounds__(256) k_gram(
    const int* __restrict__ flag,
    const void* __restrict__ x, const float* __restrict__ wt_qkvT,
    const void* __restrict__ dww, const float* __restrict__ sa,
    float* __restrict__ attn_raw, float* __restrict__ ssq_q, float* __restrict__ ssq_k) {
  if (*flag != DtF<T>::v) return;
  __shared__ bf16 ring[3][32][256];   // 3-row ring of conv outputs (q:0-15, k:16-31)
  __shared__ bf16 dwb[32][256];       // dw outputs for current row
  int b = blockIdx.z, head = blockIdx.y;
  int r0 = blockIdx.x * 8;
  int t = threadIdx.x;                // col
  size_t xbase = (size_t)b * C_ * HW_;
  const float* saw = sa + (size_t)b * HW_;

  auto convrow = [&](int r) {
    int slot = (r + 3) % 3;
    if (r < 0 || r >= H_) {
#pragma unroll
      for (int c = 0; c < 32; ++c) ring[slot][c][t] = f2b(0.f);
      return;
    }
    float acc[32];
#pragma unroll
    for (int c = 0; c < 32; ++c) acc[c] = 0.f;
    size_t xp = xbase + r * W_ + t;
    const float* wq = wt_qkvT + head * CH_;         // q block
    const float* wk = wt_qkvT + C_ + head * CH_;    // k block
    for (int i = 0; i < C_; ++i) {
      float xv = ldg<T>(x, xp + (size_t)i * HW_);
      const float* w1 = wq + i * C3_;
      const float* w2 = wk + i * C3_;
#pragma unroll
      for (int c = 0; c < 16; ++c) acc[c]      = fmaf(w1[c], xv, acc[c]);
#pragma unroll
      for (int c = 0; c < 16; ++c) acc[16 + c] = fmaf(w2[c], xv, acc[16 + c]);
    }
#pragma unroll
    for (int c = 0; c < 32; ++c) ring[slot][c][t] = f2b(acc[c]);
  };

  convrow(r0 - 1); convrow(r0); convrow(r0 + 1);
  __syncthreads();
  int c = t >> 4, d = t & 15;
  float gacc = 0.f, sacc = 0.f;
  for (int rr = r0; rr < r0 + 8; ++rr) {
    float gate = saw[rr * W_ + t];
    for (int ch = 0; ch < 32; ++ch) {
      int och = (ch < 16) ? (head * CH_ + ch) : (C_ + head * CH_ + ch - 16);
      float a = 0.f;
#pragma unroll
      for (int dy = -1; dy <= 1; ++dy) {
        int s = (rr + dy + 3) % 3;
#pragma unroll
        for (int dx = -1; dx <= 1; ++dx) {
          int cc = t + dx;
          if (cc < 0 || cc >= W_) continue;
          a = fmaf(ldg<T>(dww, och * 9 + (dy + 1) * 3 + dx + 1), b2f(ring[s][ch][cc]), a);
        }
      }
      if (ch < 16) a *= gate;
      dwb[ch][t] = f2b(a);
    }
    __syncthreads();
    for (int p = 0; p < 256; ++p) {
      int pp = (p + 4 * d + 2 * c) & 255;
      gacc = fmaf(b2f(dwb[c][pp]), b2f(dwb[16 + d][pp]), gacc);
    }
    if (t < 32) {
      for (int p = 0; p < 256; ++p) {
        int pp = (p + 2 * t) & 255;
        float v = b2f(dwb[t][pp]);
        sacc = fmaf(v, v, sacc);
      }
    }
    if (rr < r0 + 7) convrow(rr + 2);
    __syncthreads();
  }
  atomicAdd(&attn_raw[(((size_t)b * HD_ + head) * CH_ + c) * CH_ + d], gacc);
  if (t < 16)      atomicAdd(&ssq_q[((size_t)b * HD_ + head) * CH_ + t], sacc);
  else if (t < 32) atomicAdd(&ssq_k[((size_t)b * HD_ + head) * CH_ + t - 16], sacc);
}

// ----------------------------------------------- normalize + temp + softmax
template<typename T>
__global__ void k_softmax(const int* __restrict__ flag,
                          const float* __restrict__ attn_raw, const float* __restrict__ ssq_q,
                          const float* __restrict__ ssq_k, const void* __restrict__ temperature,
                          float* __restrict__ attn) {
  if (*flag != DtF<T>::v) return;
  int row = threadIdx.x;              // 256 rows = (b, head, c)
  int bh = row >> 4;
  int head = bh & 7;
  float temp = ldg<T>(temperature, head);
  float nq = fmaxf(sqrtf(ssq_q[row]), 1e-12f);
  float v[16];
#pragma unroll
  for (int d = 0; d < 16; ++d) {
    float nk = fmaxf(sqrtf(ssq_k[bh * 16 + d]), 1e-12f);
    v[d] = attn_raw[row * 16 + d] / (nq * nk) * temp;
  }
  float m = -1e30f;
#pragma unroll
  for (int d = 0; d < 16; ++d) m = fmaxf(m, v[d]);
  float s = 0.f;
#pragma unroll
  for (int d = 0; d < 16; ++d) { v[d] = expf(v[d] - m); s += v[d]; }
  float inv = 1.f / s;
#pragma unroll
  for (int d = 0; d < 16; ++d) attn[row * 16 + d] = v[d] * inv;
}

// -------- fused conv1x1(v) on-the-fly + dw3x3 + attn@v -> d_out (as "out")
template<typename T>
__global__ void __launch_bounds__(256) k_out(
    const int* __restrict__ flag,
    const void* __restrict__ x, const float* __restrict__ wt_qkvT,
    const void* __restrict__ dww, const float* __restrict__ attn,
    void* __restrict__ outb) {
  if (*flag != DtF<T>::v) return;
  __shared__ bf16 ring[3][16][256];
  int b = blockIdx.z, head = blockIdx.y, r0 = blockIdx.x * 8;
  int t = threadIdx.x;
  size_t xbase = (size_t)b * C_ * HW_;

  auto convrow = [&](int r) {
    int slot = (r + 3) % 3;
    if (r < 0 || r >= H_) {
#pragma unroll
      for (int c = 0; c < 16; ++c) ring[slot][c][t] = f2b(0.f);
      return;
    }
    float acc[16];
#pragma unroll
    for (int c = 0; c < 16; ++c) acc[c] = 0.f;
    size_t xp = xbase + r * W_ + t;
    const float* wv = wt_qkvT + 2 * C_ + head * CH_;
    for (int i = 0; i < C_; ++i) {
      float xv = ldg<T>(x, xp + (size_t)i * HW_);
      const float* w1 = wv + i * C3_;
#pragma unroll
      for (int c = 0; c < 16; ++c) acc[c] = fmaf(w1[c], xv, acc[c]);
    }
#pragma unroll
    for (int c = 0; c < 16; ++c) ring[slot][c][t] = f2b(acc[c]);
  };

  convrow(r0 - 1); convrow(r0); convrow(r0 + 1);
  __syncthreads();
  const float* ap = attn + ((size_t)b * HD_ + head) * 256;   // uniform -> s_load
  for (int rr = r0; rr < r0 + 8; ++rr) {
    float vv[16];
#pragma unroll
    for (int ch = 0; ch < 16; ++ch) {
      int och = 2 * C_ + head * CH_ + ch;
      float a = 0.f;
#pragma unroll
      for (int dy = -1; dy <= 1; ++dy) {
        int s = (rr + dy + 3) % 3;
#pragma unroll
        for (int dx = -1; dx <= 1; ++dx) {
          int cc = t + dx;
          if (cc < 0 || cc >= W_) continue;
          a = fmaf(ldg<T>(dww, och * 9 + (dy + 1) * 3 + dx + 1), b2f(ring[s][ch][cc]), a);
        }
      }
      vv[ch] = a;
    }
    size_t op = ((size_t)b * C_ + head * CH_) * (size_t)HW_ + rr * W_ + t;
#pragma unroll
    for (int c2 = 0; c2 < 16; ++c2) {
      float s = 0.f;
#pragma unroll
      for (int d = 0; d < 16; ++d) s = fmaf(ap[c2 * 16 + d], vv[d], s);
      stg<T>(outb, op + (size_t)c2 * HW_, s);
    }
    __syncthreads();
    if (rr < r0 + 7) convrow(rr + 2);
    __syncthreads();
  }
}

// ------------------------------------------------------------------- pooling
template<typename T>
__global__ void k_pool(const int* __restrict__ flag,
                       const void* __restrict__ outb, float* __restrict__ pooled) {
  if (*flag != DtF<T>::v) return;
  int ch = blockIdx.x, b = blockIdx.y;
  size_t base = ((size_t)b * C_ + ch) * (size_t)HW_;
  float s = 0.f;
  for (int i = threadIdx.x; i < HW_; i += 256) s += ldg<T>(outb, base + i);
#pragma unroll
  for (int off = 32; off > 0; off >>= 1) s += __shfl_down(s, off);
  __shared__ float wsum[4];
  int lane = threadIdx.x & 63, wv = threadIdx.x >> 6;
  if (lane == 0) wsum[wv] = s;
  __syncthreads();
  if (threadIdx.x == 0) {
    float tt = wsum[0] + wsum[1] + wsum[2] + wsum[3];
    pooled[b * C_ + ch] = tt * (1.f / HW_);
  }
}

// ------------------------------------------------------------- spectral gate
template<typename T>
__global__ void k_spec(const int* __restrict__ flag,
                       const float* __restrict__ pooled, const void* __restrict__ sp_w1,
                       const void* __restrict__ sp_w2, const void* __restrict__ sp_w3,
                       float* __restrict__ spec) {
  if (*flag != DtF<T>::v) return;
  __shared__ float g1[2][16], g2[2][16];
  int tid = threadIdx.x;
  const float RS2 = 0.70710678118654752f;
  if (tid < 32) {
    int b = tid >> 4, j = tid & 15;
    float s = 0.f;
    for (int i = 0; i < C_; ++i) s = fmaf(ldg<T>(sp_w1, j * C_ + i), pooled[b * C_ + i], s);
    g1[b][j] = 0.5f * s * (1.f + erff(s * RS2));
  }
  __syncthreads();
  if (tid < 32) {
    int b = tid >> 4, j = tid & 15;
    float s = 0.f;
    for (int l = 0; l < 16; ++l) s = fmaf(ldg<T>(sp_w2, j * 16 + l), g1[b][l], s);
    g2[b][j] = 0.5f * s * (1.f + erff(s * RS2));
  }
  __syncthreads();
  {
    int b = tid >> 7, o = tid & 127;
    float s = 0.f;
    for (int jj = 0; jj < 16; ++jj) s = fmaf(ldg<T>(sp_w3, o * 16 + jj), g2[b][jj], s);
    spec[b * C_ + o] = 1.f / (1.f + expf(-s));
  }
}

// --- z = out(d_out) + dw3x3(y)*spec staged in LDS, then proj GEMM in-place --
template<typename T>
__global__ void __launch_bounds__(256) k_zproj(
    const int* __restrict__ flag,
    const void* __restrict__ y, const void* __restrict__ dwwz,
    const float* __restrict__ spec, const float* __restrict__ wt_proj,
    void* __restrict__ dout) {
  if (*flag != DtF<T>::v) return;
  __shared__ bf16 zt[128][256];
  int b = blockIdx.y, r = blockIdx.x;
  int t = threadIdx.x;
  size_t ybase = (size_t)b * C_ * HW_;
  size_t dbase = (size_t)b * C_ * HW_;
  for (int ch = 0; ch < C_; ++ch) {
    float a = 0.f;
#pragma unroll
    for (int dy = -1; dy <= 1; ++dy) {
      int hh = r + dy;
      if (hh < 0 || hh >= H_) continue;
      size_t row = ybase + (size_t)ch * HW_ + hh * W_;
#pragma unroll
      for (int dx = -1; dx <= 1; ++dx) {
        int cc = t + dx;
        if (cc < 0 || cc >= W_) continue;
        a = fmaf(ldg<T>(dwwz, ch * 9 + (dy + 1) * 3 + dx + 1), ldg<T>(y, row + cc), a);
      }
    }
    float z = ldg<T>(dout, dbase + (size_t)ch * HW_ + r * W_ + t) + a * spec[b * C_ + ch];
    zt[ch][t] = f2b(z);
  }
  __syncthreads();
  for (int half = 0; half < 2; ++half) {
    float acc[64];
#pragma unroll
    for (int o = 0; o < 64; ++o) acc[o] = 0.f;
    for (int i = 0; i < C_; ++i) {
      float zv = b2f(zt[i][t]);
      const float* wr = wt_proj + i * C_ + half * 64;   // uniform -> s_load
#pragma unroll
      for (int o = 0; o < 64; ++o) acc[o] = fmaf(wr[o], zv, acc[o]);
    }
#pragma unroll
    for (int o = 0; o < 64; ++o)
      stg<T>(dout, dbase + (size_t)(half * 64 + o) * HW_ + r * W_ + t, acc[o]);
  }
}

// ---------------------------------------------------------------------------
extern "C" void kernel_launch(void* const* d_in, const int* in_sizes, int n_in,
                              void* d_out, int out_size, void* d_ws, size_t ws_size,
                              hipStream_t stream) {
  const void* x        = d_in[0];
  const void* y        = d_in[1];
  const void* qkv_w    = d_in[2];
  const void* qkv_dw_w = d_in[3];
  const void* proj_w   = d_in[4];
  const void* sa_w1    = d_in[5];
  const void* sa_w2    = d_in[6];
  const void* sa_w3    = d_in[7];
  const void* sp_w1    = d_in[8];
  const void* sp_w2    = d_in[9];
  const void* sp_w3    = d_in[10];
  const void* dw_w     = d_in[11];
  const void* temp     = d_in[12];

  char* ws = (char*)d_ws;
  int*   flag     = (int*)  (ws + 0);
  float* sa       = (float*)(ws + 1024);      // [2][65536] f32 = 524288
  float* attn_raw = (float*)(ws + 525312);    // 4096 f32
  float* ssq_q    = (float*)(ws + 541696);    // 256 f32
  float* ssq_k    = (float*)(ws + 542720);    // 256 f32
  float* attn     = (float*)(ws + 543744);    // 4096 f32
  float* pooled   = (float*)(ws + 560128);    // 256 f32
  float* spec     = (float*)(ws + 561152);    // 256 f32
  float* wt_qkvT  = (float*)(ws + 562176);    // [128][384] f32
  float* wt_proj  = (float*)(ws + 758784);    // [128][128] f32
  float* wt_sa1   = (float*)(ws + 824320);    // [128][16] f32 -> end 832512

  hipMemsetAsync(ws + 525312, 0, 18432, stream);  // attn_raw + ssq_q + ssq_k
  k_probe<<<1, 64, 0, stream>>>((const unsigned int*)temp, flag);

  k_wprep<bf16 ><<<192, 256, 0, stream>>>(flag, qkv_w, proj_w, sa_w1, wt_qkvT, wt_proj, wt_sa1);
  k_wprep<float><<<192, 256, 0, stream>>>(flag, qkv_w, proj_w, sa_w1, wt_qkvT, wt_proj, wt_sa1);
  k_sa<bf16 ><<<dim3(HW_ / 256, B_), 256, 0, stream>>>(flag, y, wt_sa1, sa_w2, sa_w3, sa);
  k_sa<float><<<dim3(HW_ / 256, B_), 256, 0, stream>>>(flag, y, wt_sa1, sa_w2, sa_w3, sa);
  k_gram<bf16 ><<<dim3(H_ / 8, HD_, B_), 256, 0, stream>>>(flag, x, wt_qkvT, qkv_dw_w, sa, attn_raw, ssq_q, ssq_k);
  k_gram<float><<<dim3(H_ / 8, HD_, B_), 256, 0, stream>>>(flag, x, wt_qkvT, qkv_dw_w, sa, attn_raw, ssq_q, ssq_k);
  k_softmax<bf16 ><<<1, 256, 0, stream>>>(flag, attn_raw, ssq_q, ssq_k, temp, attn);
  k_softmax<float><<<1, 256, 0, stream>>>(flag, attn_raw, ssq_q, ssq_k, temp, attn);
  k_out<bf16 ><<<dim3(H_ / 8, HD_, B_), 256, 0, stream>>>(flag, x, wt_qkvT, qkv_dw_w, attn, d_out);
  k_out<float><<<dim3(H_ / 8, HD_, B_), 256, 0, stream>>>(flag, x, wt_qkvT, qkv_dw_w, attn, d_out);
  k_pool<bf16 ><<<dim3(C_, B_), 256, 0, stream>>>(flag, d_out, pooled);
  k_pool<float><<<dim3(C_, B_), 256, 0, stream>>>(flag, d_out, pooled);
  k_spec<bf16 ><<<1, 256, 0, stream>>>(flag, pooled, sp_w1, sp_w2, sp_w3, spec);
  k_spec<float><<<1, 256, 0, stream>>>(flag, pooled, sp_w1, sp_w2, sp_w3, spec);
  k_zproj<bf16 ><<<dim3(H_, B_), 256, 0, stream>>>(flag, y, dw_w, spec, wt_proj, d_out);
  k_zproj<float><<<dim3(H_, B_), 256, 0, stream>>>(flag, y, dw_w, spec, wt_proj, d_out);
}

// Round 5
// 822.986 us; speedup vs baseline: 1.5831x; 1.5831x over previous
//
#include <hip/hip_runtime.h>
#include <hip/hip_bf16.h>

typedef __hip_bfloat16 bf16;
typedef __attribute__((ext_vector_type(8))) short short8;
typedef __attribute__((ext_vector_type(4))) float float4v;

#define B_   2
#define C_   128
#define H_   256
#define W_   256
#define HW_  65536
#define HD_  8
#define CH_  16
#define C3_  384

static __device__ __forceinline__ float b2f(bf16 v) { return __bfloat162float(v); }
static __device__ __forceinline__ bf16  f2b(float v) { return __float2bfloat16(v); }

// ---------------------------------------------------------------- weight prep
__global__ void k_wprep(const float* __restrict__ qkv_w, const float* __restrict__ proj_w,
                        const float* __restrict__ sa_w1,
                        float* __restrict__ wt_qkvT, float* __restrict__ wt_proj,
                        float* __restrict__ wt_sa1) {
  int idx = blockIdx.x * 256 + threadIdx.x;
  if (idx < C3_ * C_) { int o = idx / C_, i = idx % C_; wt_qkvT[i * C3_ + o] = qkv_w[idx]; }
  if (idx < C_ * C_)  { int o = idx / C_, i = idx % C_; wt_proj[i * C_ + o] = proj_w[idx]; }
  if (idx < 16 * C_)  { int j = idx / C_, i = idx % C_; wt_sa1[i * 16 + j] = sa_w1[idx]; }
}

// ------------------------------------------------- spatial gate sa (2 pos/thr)
__global__ void __launch_bounds__(256) k_sa(
    const float* __restrict__ y, const float* __restrict__ wt_sa1,
    const float* __restrict__ sa_w2, const float* __restrict__ sa_w3,
    float* __restrict__ sa) {
  int b = blockIdx.y;
  int p0 = (blockIdx.x * 256 + threadIdx.x) * 2;
  const float* yp = y + (size_t)b * C_ * HW_ + p0;
  float t1a[16], t1b[16];
#pragma unroll
  for (int j = 0; j < 16; ++j) { t1a[j] = 0.f; t1b[j] = 0.f; }
  for (int i = 0; i < C_; ++i) {
    float2 v = *(const float2*)(yp + (size_t)i * HW_);
    const float* wr = wt_sa1 + i * 16;   // uniform -> s_load
#pragma unroll
    for (int j = 0; j < 16; ++j) { t1a[j] = fmaf(wr[j], v.x, t1a[j]); t1b[j] = fmaf(wr[j], v.y, t1b[j]); }
  }
#pragma unroll
  for (int j = 0; j < 16; ++j) { t1a[j] = fmaxf(t1a[j], 0.f); t1b[j] = fmaxf(t1b[j], 0.f); }
  float t2a[16], t2b[16];
#pragma unroll
  for (int j = 0; j < 16; ++j) {
    float sx = 0.f, sy = 0.f;
#pragma unroll
    for (int l = 0; l < 16; ++l) { float w = sa_w2[j * 16 + l]; sx = fmaf(w, t1a[l], sx); sy = fmaf(w, t1b[l], sy); }
    t2a[j] = fmaxf(sx, 0.f); t2b[j] = fmaxf(sy, 0.f);
  }
  float sa3 = 0.f, sb3 = 0.f;
#pragma unroll
  for (int j = 0; j < 16; ++j) { float w = sa_w3[j]; sa3 = fmaf(w, t2a[j], sa3); sb3 = fmaf(w, t2b[j], sb3); }
  sa[(size_t)b * HW_ + p0]     = 1.f / (1.f + expf(-sa3));
  sa[(size_t)b * HW_ + p0 + 1] = 1.f / (1.f + expf(-sb3));
}

// -------------------------------- conv1x1 qkv GEMM: x f32 -> pre bf16 (big ws)
__global__ void __launch_bounds__(256) k_conv(
    const float* __restrict__ x, const float* __restrict__ wt, bf16* __restrict__ pre) {
  int b = blockIdx.z;
  int obase = blockIdx.y * 64;
  int pos = blockIdx.x * 256 + threadIdx.x;
  const float* ip = x + (size_t)b * C_ * HW_ + pos;
  float acc[64];
#pragma unroll
  for (int o = 0; o < 64; ++o) acc[o] = 0.f;
  float xv = ip[0];
  for (int i = 0; i < C_; ++i) {
    float xn = (i + 1 < C_) ? ip[(size_t)(i + 1) * HW_] : 0.f;
    const float* wr = wt + i * C3_ + obase;   // uniform -> s_load
#pragma unroll
    for (int o = 0; o < 64; ++o) acc[o] = fmaf(wr[o], xv, acc[o]);
    xv = xn;
  }
  bf16* op = pre + (size_t)b * C3_ * HW_ + (size_t)obase * HW_ + pos;
#pragma unroll
  for (int o = 0; o < 64; ++o) op[(size_t)o * HW_] = f2b(acc[o]);
}

// ------------ dw3x3(q,k from pre) + sa-gate + gram via MFMA + ssq (big ws)
__global__ void __launch_bounds__(256) k_dwgram(
    const bf16* __restrict__ pre, const float* __restrict__ dww,
    const float* __restrict__ sa, float* __restrict__ attn_raw,
    float* __restrict__ ssq_q, float* __restrict__ ssq_k) {
  __shared__ char smem[65536];
  bf16 (*ring)[32][256] = (bf16 (*)[32][256])smem;          // 48 KB
  bf16 (*dwb)[256] = (bf16 (*)[256])(smem + 49152);         // 16 KB, XOR-swizzled
  float* red = (float*)smem;                                 // overlay (post-loop)

  int b = blockIdx.z, head = blockIdx.y, r0 = blockIdx.x * 8;
  int t = threadIdx.x;
  const bf16* preb = pre + (size_t)b * C3_ * HW_;
  const float* saw = sa + (size_t)b * HW_;

  auto loadrow = [&](int r) {
    int slot = (r + 3) % 3;
    if (r < 0 || r >= H_) {
#pragma unroll
      for (int c = 0; c < 32; ++c) ring[slot][c][t] = f2b(0.f);
      return;
    }
#pragma unroll
    for (int c = 0; c < 32; ++c) {
      int och = (c < 16) ? (head * CH_ + c) : (C_ + head * CH_ + c - 16);
      ring[slot][c][t] = preb[(size_t)och * HW_ + r * W_ + t];
    }
  };
  loadrow(r0 - 1); loadrow(r0); loadrow(r0 + 1);
  __syncthreads();

  int lane = t & 63, wave = t >> 6;
  int m = lane & 15, quad = lane >> 4;
  int srow = t & 31, schunk = t >> 5;
  float4v acc = {0.f, 0.f, 0.f, 0.f};
  float sacc = 0.f;

  for (int rr = r0; rr < r0 + 8; ++rr) {
    float gate = saw[rr * W_ + t];
#pragma unroll
    for (int ch = 0; ch < 32; ++ch) {
      int och = (ch < 16) ? (head * CH_ + ch) : (C_ + head * CH_ + ch - 16);
      const float* wp = dww + och * 9;   // uniform -> s_load
      float a = 0.f;
#pragma unroll
      for (int dy = -1; dy <= 1; ++dy) {
        int s = (rr + dy + 3) % 3;
#pragma unroll
        for (int dx = -1; dx <= 1; ++dx) {
          int cc = t + dx;
          if (cc < 0 || cc >= W_) continue;
          a = fmaf(wp[(dy + 1) * 3 + dx + 1], b2f(ring[s][ch][cc]), a);
        }
      }
      if (ch < 16) a *= gate;
      dwb[ch][t ^ ((ch & 7) << 3)] = f2b(a);
    }
    __syncthreads();
    // gram: 2 MFMA k-steps per wave (64 positions), acc carried across rr
#pragma unroll
    for (int cn = 0; cn < 2; ++cn) {
      int p0 = wave * 64 + cn * 32;
      int ca = ((((p0 >> 3) + quad) ^ (m & 7)) << 3);
      short8 af = *(const short8*)&dwb[m][ca];        // A: q rows
      short8 bfv = *(const short8*)&dwb[16 + m][ca];  // B: k rows
      acc = __builtin_amdgcn_mfma_f32_16x16x32_bf16(af, bfv, acc, 0, 0, 0);
    }
    // ssq: thread = (row srow, chunk schunk of 32 positions)
#pragma unroll
    for (int j = 0; j < 32; ++j) {
      int p = schunk * 32 + j;
      float v = b2f(dwb[srow][p ^ ((srow & 7) << 3)]);
      sacc = fmaf(v, v, sacc);
    }
    if (rr < r0 + 7) loadrow(rr + 2);
    __syncthreads();
  }
  // C layout: D[row=quad*4+reg][col=m] -> attn_raw[c=row][d=col]
  float* ar = attn_raw + ((size_t)b * HD_ + head) * 256;
#pragma unroll
  for (int reg = 0; reg < 4; ++reg)
    atomicAdd(&ar[(quad * 4 + reg) * 16 + m], acc[reg]);
  red[t] = sacc;
  __syncthreads();
  if (t < 32) {
    float s = 0.f;
#pragma unroll
    for (int k = 0; k < 8; ++k) s += red[t + 32 * k];
    if (t < 16) atomicAdd(&ssq_q[((size_t)b * HD_ + head) * CH_ + t], s);
    else        atomicAdd(&ssq_k[((size_t)b * HD_ + head) * CH_ + t - 16], s);
  }
}

// ----------------------------------------------- normalize + temp + softmax
__global__ void k_softmax(const float* __restrict__ attn_raw, const float* __restrict__ ssq_q,
                          const float* __restrict__ ssq_k, const float* __restrict__ temperature,
                          float* __restrict__ attn) {
  int row = threadIdx.x;              // 256 rows = (b, head, c)
  int bh = row >> 4;
  int head = bh & 7;
  float temp = temperature[head];
  float nq = fmaxf(sqrtf(ssq_q[row]), 1e-12f);
  float v[16];
#pragma unroll
  for (int d = 0; d < 16; ++d) {
    float nk = fmaxf(sqrtf(ssq_k[bh * 16 + d]), 1e-12f);
    v[d] = attn_raw[row * 16 + d] / (nq * nk) * temp;
  }
  float m = -1e30f;
#pragma unroll
  for (int d = 0; d < 16; ++d) m = fmaxf(m, v[d]);
  float s = 0.f;
#pragma unroll
  for (int d = 0; d < 16; ++d) { v[d] = expf(v[d] - m); s += v[d]; }
  float inv = 1.f / s;
#pragma unroll
  for (int d = 0; d < 16; ++d) attn[row * 16 + d] = v[d] * inv;
}

// ---------------- dw3x3(v from pre) + attn@v -> d_out f32 ("out") (big ws)
__global__ void __launch_bounds__(256) k_out(
    const bf16* __restrict__ pre, const float* __restrict__ dww,
    const float* __restrict__ attn, float* __restrict__ outb) {
  __shared__ bf16 ring[3][16][256];   // 24 KB
  int b = blockIdx.z, head = blockIdx.y, r0 = blockIdx.x * 8;
  int t = threadIdx.x;
  const bf16* preb = pre + (size_t)b * C3_ * HW_ + (size_t)(2 * C_ + head * CH_) * HW_;

  auto loadrow = [&](int r) {
    int slot = (r + 3) % 3;
    if (r < 0 || r >= H_) {
#pragma unroll
      for (int c = 0; c < 16; ++c) ring[slot][c][t] = f2b(0.f);
      return;
    }
#pragma unroll
    for (int c = 0; c < 16; ++c)
      ring[slot][c][t] = preb[(size_t)c * HW_ + r * W_ + t];
  };
  loadrow(r0 - 1); loadrow(r0); loadrow(r0 + 1);
  __syncthreads();
  const float* ap = attn + ((size_t)b * HD_ + head) * 256;   // uniform -> s_load
  for (int rr = r0; rr < r0 + 8; ++rr) {
    float vv[16];
#pragma unroll
    for (int ch = 0; ch < 16; ++ch) {
      int och = 2 * C_ + head * CH_ + ch;
      const float* wp = dww + och * 9;
      float a = 0.f;
#pragma unroll
      for (int dy = -1; dy <= 1; ++dy) {
        int s = (rr + dy + 3) % 3;
#pragma unroll
        for (int dx = -1; dx <= 1; ++dx) {
          int cc = t + dx;
          if (cc < 0 || cc >= W_) continue;
          a = fmaf(wp[(dy + 1) * 3 + dx + 1], b2f(ring[s][ch][cc]), a);
        }
      }
      vv[ch] = a;
    }
    float* op = outb + ((size_t)b * C_ + head * CH_) * (size_t)HW_ + rr * W_ + t;
#pragma unroll
    for (int c2 = 0; c2 < 16; ++c2) {
      float s = 0.f;
#pragma unroll
      for (int d = 0; d < 16; ++d) s = fmaf(ap[c2 * 16 + d], vv[d], s);
      op[(size_t)c2 * HW_] = s;
    }
    __syncthreads();
    if (rr < r0 + 7) loadrow(rr + 2);
    __syncthreads();
  }
}

// ------------------------------------------------------------------- pooling
__global__ void k_pool(const float* __restrict__ outb, float* __restrict__ pooled) {
  int ch = blockIdx.x, b = blockIdx.y;
  const float* p = outb + ((size_t)b * C_ + ch) * (size_t)HW_;
  float s = 0.f;
  for (int i = threadIdx.x * 4; i < HW_; i += 1024) {
    float4 v = *(const float4*)(p + i);
    s += v.x + v.y + v.z + v.w;
  }
#pragma unroll
  for (int off = 32; off > 0; off >>= 1) s += __shfl_down(s, off);
  __shared__ float wsum[4];
  int lane = threadIdx.x & 63, wv = threadIdx.x >> 6;
  if (lane == 0) wsum[wv] = s;
  __syncthreads();
  if (threadIdx.x == 0) {
    float tt = wsum[0] + wsum[1] + wsum[2] + wsum[3];
    pooled[b * C_ + ch] = tt * (1.f / HW_);
  }
}

// ------------------------------------------------------------- spectral gate
__global__ void k_spec(const float* __restrict__ pooled, const float* __restrict__ sp_w1,
                       const float* __restrict__ sp_w2, const float* __restrict__ sp_w3,
                       float* __restrict__ spec) {
  __shared__ float g1[2][16], g2[2][16];
  int tid = threadIdx.x;
  const float RS2 = 0.70710678118654752f;
  if (tid < 32) {
    int b = tid >> 4, j = tid & 15;
    float s = 0.f;
    for (int i = 0; i < C_; ++i) s = fmaf(sp_w1[j * C_ + i], pooled[b * C_ + i], s);
    g1[b][j] = 0.5f * s * (1.f + erff(s * RS2));
  }
  __syncthreads();
  if (tid < 32) {
    int b = tid >> 4, j = tid & 15;
    float s = 0.f;
    for (int l = 0; l < 16; ++l) s = fmaf(sp_w2[j * 16 + l], g1[b][l], s);
    g2[b][j] = 0.5f * s * (1.f + erff(s * RS2));
  }
  __syncthreads();
  {
    int b = tid >> 7, o = tid & 127;
    float s = 0.f;
    for (int jj = 0; jj < 16; ++jj) s = fmaf(sp_w3[o * 16 + jj], g2[b][jj], s);
    spec[b * C_ + o] = 1.f / (1.f + expf(-s));
  }
}

// ----------- elementwise: d_out += dw3x3(y) * spec  (float4, big ws path)
__global__ void __launch_bounds__(256) k_z(
    const float* __restrict__ y, const float* __restrict__ dww,
    const float* __restrict__ spec, float* __restrict__ dout) {
  int b = blockIdx.z, ch = blockIdx.y;
  int row = blockIdx.x * 4 + (threadIdx.x >> 6);
  int c0 = (threadIdx.x & 63) * 4;
  const float* yb = y + ((size_t)b * C_ + ch) * HW_;
  const float* wp = dww + ch * 9;   // uniform -> s_load
  float acc[4] = {0.f, 0.f, 0.f, 0.f};
#pragma unroll
  for (int dy = -1; dy <= 1; ++dy) {
    int rrow = row + dy;
    if (rrow < 0 || rrow >= H_) continue;
    const float* yr = yb + rrow * W_;
    float4 cv = *(const float4*)(yr + c0);
    float lf = (c0 > 0) ? yr[c0 - 1] : 0.f;
    float rt = (c0 + 4 < W_) ? yr[c0 + 4] : 0.f;
    float w0 = wp[(dy + 1) * 3], w1 = wp[(dy + 1) * 3 + 1], w2 = wp[(dy + 1) * 3 + 2];
    float v[6] = {lf, cv.x, cv.y, cv.z, cv.w, rt};
#pragma unroll
    for (int j = 0; j < 4; ++j)
      acc[j] = fmaf(w0, v[j], fmaf(w1, v[j + 1], fmaf(w2, v[j + 2], acc[j])));
  }
  float sp = spec[b * C_ + ch];
  float* dp = dout + ((size_t)b * C_ + ch) * HW_ + row * W_ + c0;
  float4 ov = *(const float4*)dp;
  ov.x += acc[0] * sp; ov.y += acc[1] * sp; ov.z += acc[2] * sp; ov.w += acc[3] * sp;
  *(float4*)dp = ov;
}

// --------------- proj 128x128 GEMM in-place on d_out (row-block, big ws path)
__global__ void __launch_bounds__(256) k_proj(
    const float* __restrict__ wt_proj, float* __restrict__ dout) {
  __shared__ bf16 zt[128][256];
  int b = blockIdx.y, r = blockIdx.x, t = threadIdx.x;
  float* db = dout + (size_t)b * C_ * HW_;
  for (int ch = 0; ch < C_; ++ch)
    zt[ch][t] = f2b(db[(size_t)ch * HW_ + r * W_ + t]);
  __syncthreads();
#pragma unroll
  for (int half = 0; half < 2; ++half) {
    float acc[64];
#pragma unroll
    for (int o = 0; o < 64; ++o) acc[o] = 0.f;
    for (int i = 0; i < C_; ++i) {
      float zv = b2f(zt[i][t]);
      const float* wr = wt_proj + i * C_ + half * 64;   // uniform -> s_load
#pragma unroll
      for (int o = 0; o < 64; ++o) acc[o] = fmaf(wr[o], zv, acc[o]);
    }
#pragma unroll
    for (int o = 0; o < 64; ++o)
      db[(size_t)(half * 64 + o) * HW_ + r * W_ + t] = acc[o];
  }
}

// ====================== fallback kernels (small ws): round-4 fused, f32 ======
__global__ void __launch_bounds__(256) k_gram_fb(
    const float* __restrict__ x, const float* __restrict__ wt_qkvT,
    const float* __restrict__ dww, const float* __restrict__ sa,
    float* __restrict__ attn_raw, float* __restrict__ ssq_q, float* __restrict__ ssq_k) {
  __shared__ bf16 ring[3][32][256];
  __shared__ bf16 dwb[32][256];
  int b = blockIdx.z, head = blockIdx.y, r0 = blockIdx.x * 8;
  int t = threadIdx.x;
  const float* xb = x + (size_t)b * C_ * HW_;
  const float* saw = sa + (size_t)b * HW_;
  auto convrow = [&](int r) {
    int slot = (r + 3) % 3;
    if (r < 0 || r >= H_) {
#pragma unroll
      for (int c = 0; c < 32; ++c) ring[slot][c][t] = f2b(0.f);
      return;
    }
    float acc[32];
#pragma unroll
    for (int c = 0; c < 32; ++c) acc[c] = 0.f;
    const float* xp = xb + r * W_ + t;
    const float* wq = wt_qkvT + head * CH_;
    const float* wk = wt_qkvT + C_ + head * CH_;
    for (int i = 0; i < C_; ++i) {
      float xv = xp[(size_t)i * HW_];
      const float* w1 = wq + i * C3_;
      const float* w2 = wk + i * C3_;
#pragma unroll
      for (int c = 0; c < 16; ++c) acc[c]      = fmaf(w1[c], xv, acc[c]);
#pragma unroll
      for (int c = 0; c < 16; ++c) acc[16 + c] = fmaf(w2[c], xv, acc[16 + c]);
    }
#pragma unroll
    for (int c = 0; c < 32; ++c) ring[slot][c][t] = f2b(acc[c]);
  };
  convrow(r0 - 1); convrow(r0); convrow(r0 + 1);
  __syncthreads();
  int c = t >> 4, d = t & 15;
  float gacc = 0.f, sacc = 0.f;
  for (int rr = r0; rr < r0 + 8; ++rr) {
    float gate = saw[rr * W_ + t];
    for (int ch = 0; ch < 32; ++ch) {
      int och = (ch < 16) ? (head * CH_ + ch) : (C_ + head * CH_ + ch - 16);
      float a = 0.f;
#pragma unroll
      for (int dy = -1; dy <= 1; ++dy) {
        int s = (rr + dy + 3) % 3;
#pragma unroll
        for (int dx = -1; dx <= 1; ++dx) {
          int cc = t + dx;
          if (cc < 0 || cc >= W_) continue;
          a = fmaf(dww[och * 9 + (dy + 1) * 3 + dx + 1], b2f(ring[s][ch][cc]), a);
        }
      }
      if (ch < 16) a *= gate;
      dwb[ch][t] = f2b(a);
    }
    __syncthreads();
    for (int p = 0; p < 256; ++p) {
      int pp = (p + 4 * d + 2 * c) & 255;
      gacc = fmaf(b2f(dwb[c][pp]), b2f(dwb[16 + d][pp]), gacc);
    }
    if (t < 32) {
      for (int p = 0; p < 256; ++p) {
        int pp = (p + 2 * t) & 255;
        float v = b2f(dwb[t][pp]);
        sacc = fmaf(v, v, sacc);
      }
    }
    if (rr < r0 + 7) convrow(rr + 2);
    __syncthreads();
  }
  atomicAdd(&attn_raw[(((size_t)b * HD_ + head) * CH_ + c) * CH_ + d], gacc);
  if (t < 16)      atomicAdd(&ssq_q[((size_t)b * HD_ + head) * CH_ + t], sacc);
  else if (t < 32) atomicAdd(&ssq_k[((size_t)b * HD_ + head) * CH_ + t - 16], sacc);
}

__global__ void __launch_bounds__(256) k_out_fb(
    const float* __restrict__ x, const float* __restrict__ wt_qkvT,
    const float* __restrict__ dww, const float* __restrict__ attn,
    float* __restrict__ outb) {
  __shared__ bf16 ring[3][16][256];
  int b = blockIdx.z, head = blockIdx.y, r0 = blockIdx.x * 8;
  int t = threadIdx.x;
  const float* xb = x + (size_t)b * C_ * HW_;
  auto convrow = [&](int r) {
    int slot = (r + 3) % 3;
    if (r < 0 || r >= H_) {
#pragma unroll
      for (int c = 0; c < 16; ++c) ring[slot][c][t] = f2b(0.f);
      return;
    }
    float acc[16];
#pragma unroll
    for (int c = 0; c < 16; ++c) acc[c] = 0.f;
    const float* xp = xb + r * W_ + t;
    const float* wv = wt_qkvT + 2 * C_ + head * CH_;
    for (int i = 0; i < C_; ++i) {
      float xv = xp[(size_t)i * HW_];
      const float* w1 = wv + i * C3_;
#pragma unroll
      for (int c = 0; c < 16; ++c) acc[c] = fmaf(w1[c], xv, acc[c]);
    }
#pragma unroll
    for (int c = 0; c < 16; ++c) ring[slot][c][t] = f2b(acc[c]);
  };
  convrow(r0 - 1); convrow(r0); convrow(r0 + 1);
  __syncthreads();
  const float* ap = attn + ((size_t)b * HD_ + head) * 256;
  for (int rr = r0; rr < r0 + 8; ++rr) {
    float vv[16];
#pragma unroll
    for (int ch = 0; ch < 16; ++ch) {
      int och = 2 * C_ + head * CH_ + ch;
      float a = 0.f;
#pragma unroll
      for (int dy = -1; dy <= 1; ++dy) {
        int s = (rr + dy + 3) % 3;
#pragma unroll
        for (int dx = -1; dx <= 1; ++dx) {
          int cc = t + dx;
          if (cc < 0 || cc >= W_) continue;
          a = fmaf(dww[och * 9 + (dy + 1) * 3 + dx + 1], b2f(ring[s][ch][cc]), a);
        }
      }
      vv[ch] = a;
    }
    float* op = outb + ((size_t)b * C_ + head * CH_) * (size_t)HW_ + rr * W_ + t;
#pragma unroll
    for (int c2 = 0; c2 < 16; ++c2) {
      float s = 0.f;
#pragma unroll
      for (int d = 0; d < 16; ++d) s = fmaf(ap[c2 * 16 + d], vv[d], s);
      op[(size_t)c2 * HW_] = s;
    }
    __syncthreads();
    if (rr < r0 + 7) convrow(rr + 2);
    __syncthreads();
  }
}

__global__ void __launch_bounds__(256) k_zproj_fb(
    const float* __restrict__ y, const float* __restrict__ dwwz,
    const float* __restrict__ spec, const float* __restrict__ wt_proj,
    float* __restrict__ dout) {
  __shared__ bf16 zt[128][256];
  int b = blockIdx.y, r = blockIdx.x;
  int t = threadIdx.x;
  const float* yb = y + (size_t)b * C_ * HW_;
  float* db = dout + (size_t)b * C_ * HW_;
  for (int ch = 0; ch < C_; ++ch) {
    float a = 0.f;
#pragma unroll
    for (int dy = -1; dy <= 1; ++dy) {
      int hh = r + dy;
      if (hh < 0 || hh >= H_) continue;
      const float* row = yb + (size_t)ch * HW_ + hh * W_;
#pragma unroll
      for (int dx = -1; dx <= 1; ++dx) {
        int cc = t + dx;
        if (cc < 0 || cc >= W_) continue;
        a = fmaf(dwwz[ch * 9 + (dy + 1) * 3 + dx + 1], row[cc], a);
      }
    }
    float z = db[(size_t)ch * HW_ + r * W_ + t] + a * spec[b * C_ + ch];
    zt[ch][t] = f2b(z);
  }
  __syncthreads();
#pragma unroll
  for (int half = 0; half < 2; ++half) {
    float acc[64];
#pragma unroll
    for (int o = 0; o < 64; ++o) acc[o] = 0.f;
    for (int i = 0; i < C_; ++i) {
      float zv = b2f(zt[i][t]);
      const float* wr = wt_proj + i * C_ + half * 64;
#pragma unroll
      for (int o = 0; o < 64; ++o) acc[o] = fmaf(wr[o], zv, acc[o]);
    }
#pragma unroll
    for (int o = 0; o < 64; ++o)
      db[(size_t)(half * 64 + o) * HW_ + r * W_ + t] = acc[o];
  }
}

// ---------------------------------------------------------------------------
extern "C" void kernel_launch(void* const* d_in, const int* in_sizes, int n_in,
                              void* d_out, int out_size, void* d_ws, size_t ws_size,
                              hipStream_t stream) {
  const float* x        = (const float*)d_in[0];
  const float* y        = (const float*)d_in[1];
  const float* qkv_w    = (const float*)d_in[2];
  const float* qkv_dw_w = (const float*)d_in[3];
  const float* proj_w   = (const float*)d_in[4];
  const float* sa_w1    = (const float*)d_in[5];
  const float* sa_w2    = (const float*)d_in[6];
  const float* sa_w3    = (const float*)d_in[7];
  const float* sp_w1    = (const float*)d_in[8];
  const float* sp_w2    = (const float*)d_in[9];
  const float* sp_w3    = (const float*)d_in[10];
  const float* dw_w     = (const float*)d_in[11];
  const float* temp     = (const float*)d_in[12];
  float* out = (float*)d_out;

  char* ws = (char*)d_ws;
  float* attn_raw = (float*)(ws + 0);         // 4096 f32
  float* ssq_q    = (float*)(ws + 16384);     // 256 f32
  float* ssq_k    = (float*)(ws + 17408);     // 256 f32
  float* attn     = (float*)(ws + 18432);     // 4096 f32
  float* pooled   = (float*)(ws + 34816);     // 256 f32
  float* spec     = (float*)(ws + 35840);     // 256 f32
  float* wt_qkvT  = (float*)(ws + 36864);     // [128][384] f32
  float* wt_proj  = (float*)(ws + 233472);    // [128][128] f32
  float* wt_sa1   = (float*)(ws + 299008);    // [128][16] f32
  float* sa       = (float*)(ws + 307200);    // [2][65536] f32 -> 831488
  bf16*  pre      = (bf16*) (ws + 1048576);   // [2][384][65536] bf16 = 100663296
  const size_t NEED = 1048576 + 100663296;    // 101,711,872
  bool big = ws_size >= NEED;

  hipMemsetAsync(ws, 0, 18432, stream);       // attn_raw + ssq_q + ssq_k

  k_wprep<<<192, 256, 0, stream>>>(qkv_w, proj_w, sa_w1, wt_qkvT, wt_proj, wt_sa1);
  k_sa<<<dim3(HW_ / 512, B_), 256, 0, stream>>>(y, wt_sa1, sa_w2, sa_w3, sa);
  if (big) {
    k_conv<<<dim3(HW_ / 256, C3_ / 64, B_), 256, 0, stream>>>(x, wt_qkvT, pre);
    k_dwgram<<<dim3(H_ / 8, HD_, B_), 256, 0, stream>>>(pre, qkv_dw_w, sa,
                                                        attn_raw, ssq_q, ssq_k);
    k_softmax<<<1, 256, 0, stream>>>(attn_raw, ssq_q, ssq_k, temp, attn);
    k_out<<<dim3(H_ / 8, HD_, B_), 256, 0, stream>>>(pre, qkv_dw_w, attn, out);
  } else {
    k_gram_fb<<<dim3(H_ / 8, HD_, B_), 256, 0, stream>>>(x, wt_qkvT, qkv_dw_w, sa,
                                                         attn_raw, ssq_q, ssq_k);
    k_softmax<<<1, 256, 0, stream>>>(attn_raw, ssq_q, ssq_k, temp, attn);
    k_out_fb<<<dim3(H_ / 8, HD_, B_), 256, 0, stream>>>(x, wt_qkvT, qkv_dw_w, attn, out);
  }
  k_pool<<<dim3(C_, B_), 256, 0, stream>>>(out, pooled);
  k_spec<<<1, 256, 0, stream>>>(pooled, sp_w1, sp_w2, sp_w3, spec);
  if (big) {
    k_z<<<dim3(H_ / 4, C_, B_), 256, 0, stream>>>(y, dw_w, spec, out);
    k_proj<<<dim3(H_, B_), 256, 0, stream>>>(wt_proj, out);
  } else {
    k_zproj_fb<<<dim3(H_, B_), 256, 0, stream>>>(y, dw_w, spec, wt_proj, out);
  }
}